// Round 2
// baseline (441.525 us; speedup 1.0000x reference)
//
#include <hip/hip_runtime.h>

typedef unsigned short u16;

constexpr int kN   = 512;
constexpr int kIN  = 256;
constexpr int kHID = 256;
constexpr int kHD  = 64;
constexpr int kOUT = 256;

// ---------- bf16 helpers ----------
__device__ __forceinline__ float us2f(u16 u){
  union { unsigned int i; float f; } c; c.i = ((unsigned int)u) << 16; return c.f;
}
__device__ __forceinline__ u16 f2us(float f){
  union { float f; unsigned int i; } c; c.f = f;
  unsigned int r = c.i + 0x7fff + ((c.i >> 16) & 1);
  return (u16)(r >> 16);
}

// ---------- dtype probe: decide bf16 vs fp32 input buffers ----------
// Reads first 4096 u32 words of V. If underlying data is fp32, the LOW u16 of
// each word is mantissa garbage -> decoded-as-bf16 magnitude is wild (~48%
// exceed 32). If data is bf16 (N(0,1) features), low u16 is a real value,
// |x| <= ~5. flag: 1 = fp32 inputs, 0 = bf16 inputs.
__global__ void k_probe(const unsigned int* __restrict__ V, int* __restrict__ flag){
  __shared__ int cnt;
  if (threadIdx.x == 0) cnt = 0;
  __syncthreads();
  int c = 0;
  for (int k = threadIdx.x; k < 4096; k += 256){
    float x = us2f((u16)(V[k] & 0xffffu));
    float ax = fabsf(x);
    if (!(ax <= 32.0f)) c++;   // also catches NaN/Inf bit patterns
  }
  atomicAdd(&cnt, c);
  __syncthreads();
  if (threadIdx.x == 0) *flag = (cnt > 64) ? 1 : 0;
}

// ---------- convert all float tensors to fp32 in workspace ----------
struct ConvArgs { const void* src[23]; float* dst[23]; int n[23]; };

__global__ void k_convert_all(ConvArgs a, const int* __restrict__ flag){
  bool f32 = (*flag != 0);
  int stride = gridDim.x * blockDim.x;
  int t = blockIdx.x * blockDim.x + threadIdx.x;
  for (int s = 0; s < 23; ++s){
    int n = a.n[s];
    const float* sf = (const float*)a.src[s];
    const u16*   sb = (const u16*)a.src[s];
    float* d = a.dst[s];
    for (int i = t; i < n; i += stride)
      d[i] = f32 ? sf[i] : us2f(sb[i]);
  }
}

// ---------- block reduction (blockDim multiple of 64, <=512) ----------
__device__ __forceinline__ float blk_red(float v, float* tmp, bool isMax){
  int lane = threadIdx.x & 63, wv = threadIdx.x >> 6;
  #pragma unroll
  for (int o = 32; o > 0; o >>= 1){
    float t = __shfl_down(v, o, 64);
    v = isMax ? fmaxf(v, t) : (v + t);
  }
  __syncthreads();
  if (lane == 0) tmp[wv] = v;
  __syncthreads();
  int nw = (blockDim.x + 63) >> 6;
  float r = tmp[0];
  for (int i = 1; i < nw; ++i) r = isMax ? fmaxf(r, tmp[i]) : (r + tmp[i]);
  return r;
}

// ---------- row-per-block GEMM: C[i,o] = act(concat(Xa_i,Xb_i) . W[o,:] + bias[o]) ----------
// All fp32. blockDim.x = Nout = C leading dim. ldw multiple of 4.
__global__ void k_gemm(const float* __restrict__ Xa, int K1,
                       const float* __restrict__ Xb, int Ktot,
                       const float* __restrict__ W, int ldw,
                       const float* __restrict__ bias, int doRelu,
                       float* __restrict__ C)
{
  __shared__ float x[768];
  int i = blockIdx.x, nt = blockDim.x;
  for (int k = threadIdx.x; k < Ktot; k += nt)
    x[k] = (k < K1) ? Xa[(size_t)i*K1 + k] : Xb[(size_t)i*(Ktot-K1) + (k-K1)];
  __syncthreads();
  int o = threadIdx.x;
  const float4* wr = (const float4*)(W + (size_t)o * ldw);
  float acc = bias ? bias[o] : 0.0f;
  for (int kb = 0; kb < Ktot; kb += 4){
    float4 q = *wr++;
    acc += x[kb+0]*q.x + x[kb+1]*q.y + x[kb+2]*q.z + x[kb+3]*q.w;
  }
  if (doRelu) acc = fmaxf(acc, 0.0f);
  C[(size_t)i*nt + o] = acc;
}

// ---------- e1[j] = Wh1[j,:] . sa1 ----------
__global__ void k_e1(const float* __restrict__ Wh1, const float* __restrict__ sa1,
                     float* __restrict__ e1)
{
  int i = blockIdx.x, lane = threadIdx.x; // block 64
  float a = 0.f;
  for (int k = lane; k < kHID; k += 64) a += Wh1[(size_t)i*kHID + k] * sa1[k];
  #pragma unroll
  for (int o = 32; o > 0; o >>= 1) a += __shfl_down(a, o, 64);
  if (lane == 0) e1[i] = a;
}

// ---------- H1: row-wise masked softmax over e1[j], weighted sum of Wh1 rows ----------
__global__ void k_h1(const int* __restrict__ adj, const float* __restrict__ e1,
                     const float* __restrict__ Wh1, float* __restrict__ H1)
{
  __shared__ float w[4][kN];
  __shared__ float red[8];
  int i0 = blockIdx.x * 4, tid = threadIdx.x; // block 256
  float invz[4];
  #pragma unroll
  for (int r = 0; r < 4; ++r){
    int i = i0 + r;
    int m0 = adj[(size_t)i*kN + tid];
    int m1 = adj[(size_t)i*kN + tid + 256];
    float ea = e1[tid], eb = e1[tid+256];
    float v0 = m0 ? ea : -1e30f;
    float v1 = m1 ? eb : -1e30f;
    float m = blk_red(fmaxf(v0, v1), red, true);
    float w0 = m0 ? expf(ea - m) : 0.0f;
    float w1 = m1 ? expf(eb - m) : 0.0f;
    w[r][tid] = w0; w[r][tid+256] = w1;
    float z = blk_red(w0 + w1, red, false);
    invz[r] = 1.0f / z;
  }
  __syncthreads();
  float a0=0,a1=0,a2=0,a3=0;
  for (int j = 0; j < kN; ++j){
    float wh = Wh1[(size_t)j*kHID + tid];
    a0 += w[0][j]*wh; a1 += w[1][j]*wh; a2 += w[2][j]*wh; a3 += w[3][j]*wh;
  }
  H1[(size_t)(i0+0)*kHID+tid] = a0*invz[0];
  H1[(size_t)(i0+1)*kHID+tid] = a1*invz[1];
  H1[(size_t)(i0+2)*kHID+tid] = a2*invz[2];
  H1[(size_t)(i0+3)*kHID+tid] = a3*invz[3];
}

// ---------- u = ce_w2^T (ca0+ca1), beta = ce_b2 . (ca0+ca1) ----------
__global__ void k_ub(const float* __restrict__ ce_w2, const float* __restrict__ ce_b2,
                     const float* __restrict__ ca0, const float* __restrict__ ca1,
                     float* __restrict__ u, float* __restrict__ beta)
{
  __shared__ float c[kHD];
  int tid = threadIdx.x; // 256
  if (tid < kHD) c[tid] = ca0[tid] + ca1[tid];
  __syncthreads();
  float a = 0.f;
  for (int d = 0; d < kHD; ++d) a += ce_w2[(size_t)d*kHID + tid] * c[d];
  u[tid] = a;
  if (tid == 0){
    float b = 0.f;
    for (int d = 0; d < kHD; ++d) b += ce_b2[d] * c[d];
    *beta = b;
  }
}

// ---------- s2[i,j] = relu(A_i + B_j + b1) . u + beta (diag -> -1e30); rowmax/rowZ ----------
__global__ void k_s2(const float* __restrict__ A, const float* __restrict__ Bm,
                     const float* __restrict__ ce_b1,
                     const float* __restrict__ u, const float* __restrict__ beta,
                     float* __restrict__ s2, float* __restrict__ rowmax,
                     float* __restrict__ rowZ)
{
  __shared__ float aib[4][kHID];
  __shared__ float uu[kHID];
  __shared__ float red[8];
  int i0 = blockIdx.x * 4, tid = threadIdx.x; // block 256
  uu[tid] = u[tid];
  float b1v = ce_b1[tid];
  #pragma unroll
  for (int r = 0; r < 4; ++r) aib[r][tid] = A[(size_t)(i0+r)*kHID + tid] + b1v;
  __syncthreads();
  float bet = *beta;
  float sv[4][2];
  #pragma unroll
  for (int t = 0; t < 2; ++t){
    int j = tid + t*256;
    float a0=bet, a1=bet, a2=bet, a3=bet;
    const float4* bp = (const float4*)(Bm + (size_t)j*kHID);
    for (int k4 = 0; k4 < kHID/4; ++k4){
      float4 b = bp[k4];
      int k = k4*4;
      a0 += fmaxf(aib[0][k+0]+b.x,0.f)*uu[k+0] + fmaxf(aib[0][k+1]+b.y,0.f)*uu[k+1]
          + fmaxf(aib[0][k+2]+b.z,0.f)*uu[k+2] + fmaxf(aib[0][k+3]+b.w,0.f)*uu[k+3];
      a1 += fmaxf(aib[1][k+0]+b.x,0.f)*uu[k+0] + fmaxf(aib[1][k+1]+b.y,0.f)*uu[k+1]
          + fmaxf(aib[1][k+2]+b.z,0.f)*uu[k+2] + fmaxf(aib[1][k+3]+b.w,0.f)*uu[k+3];
      a2 += fmaxf(aib[2][k+0]+b.x,0.f)*uu[k+0] + fmaxf(aib[2][k+1]+b.y,0.f)*uu[k+1]
          + fmaxf(aib[2][k+2]+b.z,0.f)*uu[k+2] + fmaxf(aib[2][k+3]+b.w,0.f)*uu[k+3];
      a3 += fmaxf(aib[3][k+0]+b.x,0.f)*uu[k+0] + fmaxf(aib[3][k+1]+b.y,0.f)*uu[k+1]
          + fmaxf(aib[3][k+2]+b.z,0.f)*uu[k+2] + fmaxf(aib[3][k+3]+b.w,0.f)*uu[k+3];
    }
    if (j == i0+0) a0 = -1e30f;
    if (j == i0+1) a1 = -1e30f;
    if (j == i0+2) a2 = -1e30f;
    if (j == i0+3) a3 = -1e30f;
    s2[(size_t)(i0+0)*kN + j] = a0;
    s2[(size_t)(i0+1)*kN + j] = a1;
    s2[(size_t)(i0+2)*kN + j] = a2;
    s2[(size_t)(i0+3)*kN + j] = a3;
    sv[0][t]=a0; sv[1][t]=a1; sv[2][t]=a2; sv[3][t]=a3;
  }
  #pragma unroll
  for (int r = 0; r < 4; ++r){
    float m = blk_red(fmaxf(sv[r][0], sv[r][1]), red, true);
    float z = blk_red(expf(sv[r][0]-m) + expf(sv[r][1]-m), red, false);
    if (tid == 0){ rowmax[i0+r] = m; rowZ[i0+r] = z; }
  }
}

// ---------- global softmax stats over s2 ----------
__global__ void k_mz(const float* __restrict__ rowmax, const float* __restrict__ rowZ,
                     float* __restrict__ MZ)
{
  __shared__ float red[8];
  int tid = threadIdx.x; // 256
  float m = fmaxf(rowmax[tid], rowmax[tid+256]);
  m = blk_red(m, red, true);
  float z = rowZ[tid]*expf(rowmax[tid]-m) + rowZ[tid+256]*expf(rowmax[tid+256]-m);
  z = blk_red(z, red, false);
  if (tid == 0){ MZ[0] = m; MZ[1] = z; }
}

// ---------- gpart[i,k] = sum_j a2[i,j] * relu(A_i[k]+B_j[k]+b1[k]) ----------
__global__ void k_gpart(const float* __restrict__ A, const float* __restrict__ Bm,
                        const float* __restrict__ ce_b1,
                        const float* __restrict__ s2, const float* __restrict__ MZ,
                        float* __restrict__ gpart)
{
  __shared__ float w[4][kN];
  int i0 = blockIdx.x * 4, tid = threadIdx.x; // block 256
  float M = MZ[0], invZ = 1.0f / MZ[1];
  #pragma unroll
  for (int r = 0; r < 4; ++r){
    w[r][tid]     = expf(s2[(size_t)(i0+r)*kN + tid]       - M) * invZ;
    w[r][tid+256] = expf(s2[(size_t)(i0+r)*kN + tid + 256] - M) * invZ;
  }
  float b1v = ce_b1[tid];
  float ai0 = A[(size_t)(i0+0)*kHID + tid] + b1v;
  float ai1 = A[(size_t)(i0+1)*kHID + tid] + b1v;
  float ai2 = A[(size_t)(i0+2)*kHID + tid] + b1v;
  float ai3 = A[(size_t)(i0+3)*kHID + tid] + b1v;
  __syncthreads();
  float g0=0,g1=0,g2=0,g3=0;
  for (int j = 0; j < kN; ++j){
    float bj = Bm[(size_t)j*kHID + tid];
    g0 += w[0][j]*fmaxf(ai0+bj, 0.f);
    g1 += w[1][j]*fmaxf(ai1+bj, 0.f);
    g2 += w[2][j]*fmaxf(ai2+bj, 0.f);
    g3 += w[3][j]*fmaxf(ai3+bj, 0.f);
  }
  gpart[(size_t)(i0+0)*kHID+tid]=g0;
  gpart[(size_t)(i0+1)*kHID+tid]=g1;
  gpart[(size_t)(i0+2)*kHID+tid]=g2;
  gpart[(size_t)(i0+3)*kHID+tid]=g3;
}

// ---------- g = colsum(gpart); H2vec = g @ ce_w2^T + ce_b2 ----------
__global__ void k_h2(const float* __restrict__ gpart, const float* __restrict__ ce_w2,
                     const float* __restrict__ ce_b2, float* __restrict__ H2vec)
{
  __shared__ float g[kHID];
  int tid = threadIdx.x; // 256, single block
  float a = 0.f;
  for (int i = 0; i < kN; ++i) a += gpart[(size_t)i*kHID + tid];
  g[tid] = a;
  __syncthreads();
  if (tid < kHD){
    float h = ce_b2[tid];
    for (int k = 0; k < kHID; ++k) h += g[k] * ce_w2[(size_t)tid*kHID + k];
    H2vec[tid] = h;
  }
}

// ---------- H3[i,d] = mean(tf[0..i, d]) ----------
__global__ void k_h3(const float* __restrict__ tf, float* __restrict__ H3)
{
  __shared__ float s[kN];
  int d = blockIdx.x, i = threadIdx.x; // block 512
  s[i] = tf[(size_t)i*kHD + d];
  __syncthreads();
  for (int off = 1; off < kN; off <<= 1){
    float t = (i >= off) ? s[i-off] : 0.0f;
    __syncthreads();
    s[i] += t;
    __syncthreads();
  }
  H3[(size_t)i*kHD + d] = s[i] / (float)(i+1);
}

// ---------- first two neighbors per row ----------
__global__ void k_pairsel(const int* __restrict__ adj, int* __restrict__ nbr)
{
  int i = blockIdx.x * blockDim.x + threadIdx.x; // 512 threads total
  int j0 = -1, j1 = -1;
  for (int j = 0; j < kN; ++j){
    if (adj[(size_t)i*kN + j] != 0){
      if (j0 < 0) j0 = j;
      else { j1 = j; break; }
    }
  }
  if (j1 < 0) j0 = -1;
  nbr[2*i] = j0; nbr[2*i+1] = j1;
}

// ---------- Xp = [V | n0 | n1] (fp32, gathered) ----------
__global__ void k_packxp(const float* __restrict__ Vf, const int* __restrict__ nbr,
                         float* __restrict__ Xp)
{
  int i = blockIdx.x, k = threadIdx.x; // block 256
  int j0 = nbr[2*i], j1 = nbr[2*i+1];
  Xp[(size_t)i*768 + k]       = Vf[(size_t)i*kIN + k];
  Xp[(size_t)i*768 + 256 + k] = (j0 >= 0) ? Vf[(size_t)j0*kIN + k] : 0.0f;
  Xp[(size_t)i*768 + 512 + k] = (j1 >= 0) ? Vf[(size_t)j1*kIN + k] : 0.0f;
}

// ---------- H4v = colsum(cf) ----------
__global__ void k_h4(const float* __restrict__ cf, float* __restrict__ H4v)
{
  int d = threadIdx.x; // block 64, single block
  float a = 0.f;
  for (int i = 0; i < kN; ++i) a += cf[(size_t)i*kHD + d];
  H4v[d] = a;
}

// ---------- out2 = [H1 | H2vec | H3 | H4col] @ W2^T (ld 385) ----------
__global__ void k_out2(const float* __restrict__ H1, const float* __restrict__ H2vec,
                       const float* __restrict__ H3, const float* __restrict__ H4v,
                       const float* __restrict__ W2, float* __restrict__ out2)
{
  __shared__ float h1r[kHID];
  __shared__ float h3r[kHD];
  __shared__ float h2v[kHD];
  __shared__ float h4s[1];
  int i = blockIdx.x, o = threadIdx.x; // block 256
  h1r[o] = H1[(size_t)i*kHID + o];
  if (o < kHD){ h3r[o] = H3[(size_t)i*kHD + o]; h2v[o] = H2vec[o]; }
  if (o == 0) h4s[0] = (i < kHD) ? H4v[i] : 0.0f;
  __syncthreads();
  const float* wr = W2 + (size_t)o * 385;
  float acc = 0.f;
  for (int k = 0; k < kHID; ++k) acc += h1r[k] * wr[k];
  for (int d = 0; d < kHD; ++d)  acc += h2v[d] * wr[256+d];
  for (int d = 0; d < kHD; ++d)  acc += h3r[d] * wr[320+d];
  acc += h4s[0] * wr[384];
  out2[(size_t)i*kOUT + o] = acc;
}

// ---------- out = elu(layernorm(out2 @ op_w^T + op_b)), store per dtype flag ----------
__global__ void k_final(const float* __restrict__ out2, const float* __restrict__ op_w,
                        const float* __restrict__ op_b, const float* __restrict__ ln_g,
                        const float* __restrict__ ln_b, const int* __restrict__ flag,
                        void* __restrict__ out)
{
  __shared__ float row[kOUT];
  __shared__ float red[8];
  int i = blockIdx.x, o = threadIdx.x; // block 256
  row[o] = out2[(size_t)i*kOUT + o];
  __syncthreads();
  const float4* wr = (const float4*)(op_w + (size_t)o * kOUT);
  float acc = op_b[o];
  for (int kb = 0; kb < kOUT; kb += 4){
    float4 q = *wr++;
    acc += row[kb+0]*q.x + row[kb+1]*q.y + row[kb+2]*q.z + row[kb+3]*q.w;
  }
  float mu = blk_red(acc, red, false) * (1.0f/kOUT);
  float dv = acc - mu;
  float var = blk_red(dv*dv, red, false) * (1.0f/kOUT);
  float y = dv * rsqrtf(var + 1e-5f) * ln_g[o] + ln_b[o];
  y = (y > 0.f) ? y : expm1f(y);
  if (*flag) ((float*)out)[(size_t)i*kOUT + o] = y;
  else       ((u16*)out)[(size_t)i*kOUT + o]   = f2us(y);
}

extern "C" void kernel_launch(void* const* d_in, const int* in_sizes, int n_in,
                              void* d_out, int out_size, void* d_ws, size_t ws_size,
                              hipStream_t stream)
{
  const void* V     = d_in[0];
  const int*  adj   = (const int*)d_in[1];
  const void* prev  = d_in[2];
  const void* W1    = d_in[3];
  // d_in[4] = sa0 : dead (row-shift invariant softmax)
  const void* sa1   = d_in[5];
  const void* ce_w1 = d_in[6];
  const void* ce_b1 = d_in[7];
  const void* ce_w2 = d_in[8];
  const void* ce_b2 = d_in[9];
  const void* ca0   = d_in[10];
  const void* ca1   = d_in[11];
  const void* te_w1 = d_in[12];
  const void* te_b1 = d_in[13];
  const void* te_w2 = d_in[14];
  const void* te_b2 = d_in[15];
  // d_in[16,17] = ta0,ta1 : dead (uniform causal softmax)
  const void* pe_w1 = d_in[18];
  const void* pe_b1 = d_in[19];
  const void* pe_w2 = d_in[20];
  const void* pe_b2 = d_in[21];
  // d_in[22,23] = pa0,pa1 : dead
  const void* W2    = d_in[24];
  const void* op_w  = d_in[25];
  const void* op_b  = d_in[26];
  const void* ln_g  = d_in[27];
  const void* ln_b  = d_in[28];

  // ---- workspace layout (floats). All segment sizes multiple of 16 floats. ----
  float* ws  = (float*)d_ws;
  int*  flag = (int*)ws;               // 16 floats reserved
  float* p   = ws + 16;
  float* Vf   = p; p += 131072;
  float* prevf= p; p += 131072;
  float* W1f  = p; p += 65536;
  float* sa1f = p; p += 256;
  float* cw1f = p; p += 131072;
  float* cb1f = p; p += 256;
  float* cw2f = p; p += 16384;
  float* cb2f = p; p += 64;
  float* ca0f = p; p += 64;
  float* ca1f = p; p += 64;
  float* tw1f = p; p += 131072;
  float* tb1f = p; p += 256;
  float* tw2f = p; p += 16384;
  float* tb2f = p; p += 64;
  float* pw1f = p; p += 196608;
  float* pb1f = p; p += 256;
  float* pw2f = p; p += 16384;
  float* pb2f = p; p += 64;
  float* W2f  = p; p += 98560;
  float* opwf = p; p += 65536;
  float* opbf = p; p += 256;
  float* lngf = p; p += 256;
  float* lnbf = p; p += 256;
  float* Wh1      = p; p += 131072;
  float* e1v      = p; p += 512;
  float* H1       = p; p += 131072;
  float* Am       = p; p += 131072;
  float* Bm       = p; p += 131072;
  float* uvec     = p; p += 256;
  float* beta     = p; p += 16;
  float* s2       = p; p += 262144;
  float* rowmax   = p; p += 512;
  float* rowZ     = p; p += 512;
  float* MZ       = p; p += 16;
  float* gpart    = p; p += 131072;
  float* H2vec    = p; p += 64;
  float* hidden_t = p; p += 131072;
  float* tfm      = p; p += 32768;
  float* H3       = p; p += 32768;
  int*   nbr      = (int*)p; p += 1024;
  float* Xp       = p; p += 393216;
  float* hidden_p = p; p += 131072;
  float* cfm      = p; p += 32768;
  float* H4v      = p; p += 64;
  float* out2     = p; p += 131072;

  // ---- dtype probe + input widening ----
  k_probe<<<1, 256, 0, stream>>>((const unsigned int*)V, flag);
  ConvArgs ca;
  const void* srcs[23] = {V, prev, W1, sa1, ce_w1, ce_b1, ce_w2, ce_b2, ca0, ca1,
                          te_w1, te_b1, te_w2, te_b2, pe_w1, pe_b1, pe_w2, pe_b2,
                          W2, op_w, op_b, ln_g, ln_b};
  float* dsts[23] = {Vf, prevf, W1f, sa1f, cw1f, cb1f, cw2f, cb2f, ca0f, ca1f,
                     tw1f, tb1f, tw2f, tb2f, pw1f, pb1f, pw2f, pb2f,
                     W2f, opwf, opbf, lngf, lnbf};
  int ns[23] = {131072, 131072, 65536, 256, 131072, 256, 16384, 64, 64, 64,
                131072, 256, 16384, 64, 196608, 256, 16384, 64,
                98560, 65536, 256, 256, 256};
  for (int s = 0; s < 23; ++s){ ca.src[s] = srcs[s]; ca.dst[s] = dsts[s]; ca.n[s] = ns[s]; }
  k_convert_all<<<512, 256, 0, stream>>>(ca, flag);

  // --- GAT branch (H1) ---
  k_gemm<<<kN, 256, 0, stream>>>(Vf, kIN, Vf, kIN, W1f, kIN, nullptr, 0, Wh1);
  k_e1<<<kN, 64, 0, stream>>>(Wh1, sa1f, e1v);
  k_h1<<<kN/4, 256, 0, stream>>>(adj, e1v, Wh1, H1);

  // --- cross-edge branch (H2) ---
  k_gemm<<<kN, 256, 0, stream>>>(Vf, kIN, Vf, kIN, cw1f, 2*kIN, nullptr, 0, Am);
  k_gemm<<<kN, 256, 0, stream>>>(Vf, kIN, Vf, kIN, cw1f + kIN, 2*kIN, nullptr, 0, Bm);
  k_ub<<<1, 256, 0, stream>>>(cw2f, cb2f, ca0f, ca1f, uvec, beta);
  k_s2<<<kN/4, 256, 0, stream>>>(Am, Bm, cb1f, uvec, beta, s2, rowmax, rowZ);
  k_mz<<<1, 256, 0, stream>>>(rowmax, rowZ, MZ);
  k_gpart<<<kN/4, 256, 0, stream>>>(Am, Bm, cb1f, s2, MZ, gpart);
  k_h2<<<1, 256, 0, stream>>>(gpart, cw2f, cb2f, H2vec);

  // --- temporal branch (H3) ---
  k_gemm<<<kN, 256, 0, stream>>>(Vf, kIN, prevf, kIN + kHID, tw1f, kIN + kHID, tb1f, 1, hidden_t);
  k_gemm<<<kN, 64, 0, stream>>>(hidden_t, kHID, hidden_t, kHID, tw2f, kHID, tb2f, 0, tfm);
  k_h3<<<kHD, kN, 0, stream>>>(tfm, H3);

  // --- pair branch (H4) ---
  k_pairsel<<<2, 256, 0, stream>>>(adj, nbr);
  k_packxp<<<kN, 256, 0, stream>>>(Vf, nbr, Xp);
  k_gemm<<<kN, 256, 0, stream>>>(Xp, 3*kIN, Xp, 3*kIN, pw1f, 3*kIN, pb1f, 1, hidden_p);
  k_gemm<<<kN, 64, 0, stream>>>(hidden_p, kHID, hidden_p, kHID, pw2f, kHID, pb2f, 0, cfm);
  k_h4<<<1, 64, 0, stream>>>(cfm, H4v);

  // --- combine + output head ---
  k_out2<<<kN, 256, 0, stream>>>(H1, H2vec, H3, H4v, W2f, out2);
  k_final<<<kN, 256, 0, stream>>>(out2, opwf, opbf, lngf, lnbf, flag, d_out);
}